// Round 1
// baseline (485.091 us; speedup 1.0000x reference)
//
#include <hip/hip_runtime.h>
#include <hip/hip_bf16.h>
#include <math.h>

#define NH 16
#define DH 128
#define DM 2048
#define BB 2
#define TT 2048

typedef unsigned short u16;
typedef __attribute__((ext_vector_type(8))) __bf16 bf16x8;
typedef __attribute__((ext_vector_type(8))) u16 u16x8;
typedef __attribute__((ext_vector_type(4))) u16 u16x4;
typedef __attribute__((ext_vector_type(4))) float f32x4;

__device__ __forceinline__ float bf2f(u16 a){
  union { unsigned u; float f; } v; v.u = ((unsigned)a) << 16; return v.f;
}
__device__ __forceinline__ u16 f2bf(float f){
  union { float f; unsigned u; } v; v.f = f;
  unsigned r = v.u + 0x7fffu + ((v.u >> 16) & 1u);  // RNE
  return (u16)(r >> 16);
}

// async global->LDS, 16B per lane. LDS dest = wave-uniform base + lane*16.
typedef const __attribute__((address_space(1))) unsigned int* gas_p;
typedef __attribute__((address_space(3))) unsigned int* las_p;
__device__ __forceinline__ void gl_lds16(const u16* g, u16* lds_uniform_base){
  __builtin_amdgcn_global_load_lds((gas_p)(const void*)g,
                                   (las_p)(void*)lds_uniform_base, 16, 0, 0);
}

// ---------------- fp32 -> bf16 elementwise, 4/thread ----------------
__global__ __launch_bounds__(256)
void cvt_f32_bf16(const float* __restrict__ src, u16* __restrict__ dst, int n4){
  const int i = blockIdx.x * 256 + threadIdx.x;
  if (i >= n4) return;
  const f32x4 v = *(const f32x4*)(src + (size_t)i * 4);
  u16x4 o;
  #pragma unroll
  for (int j = 0; j < 4; j++) o[j] = f2bf(v[j]);
  *(u16x4*)(dst + (size_t)i * 4) = o;
}

// ---------------- W fp32 [K,N] -> Wt bf16 [N,K] (single) ----------------
__global__ __launch_bounds__(256)
void transpose2048(const float* __restrict__ W, u16* __restrict__ Wt){
  __shared__ u16 tile[32][33];
  const int tx = threadIdx.x, ty = threadIdx.y;
  const int bx = blockIdx.x * 32, by = blockIdx.y * 32;
  #pragma unroll
  for (int i = 0; i < 32; i += 8)
    tile[ty + i][tx] = f2bf(W[(size_t)(by + ty + i) * DM + bx + tx]);
  __syncthreads();
  #pragma unroll
  for (int i = 0; i < 32; i += 8)
    Wt[(size_t)(bx + ty + i) * DM + by + tx] = tile[tx][ty + i];
}

// ---------------- 3 weights fused via z ----------------
__global__ __launch_bounds__(256)
void transpose3(const float* __restrict__ w0, const float* __restrict__ w1,
                const float* __restrict__ w2, u16* __restrict__ dst){
  __shared__ u16 tile[32][33];
  const int z = blockIdx.z;
  const float* W = (z == 0) ? w0 : (z == 1) ? w1 : w2;
  u16* Wt = dst + (size_t)z * DM * DM;
  const int tx = threadIdx.x, ty = threadIdx.y;
  const int bx = blockIdx.x * 32, by = blockIdx.y * 32;
  #pragma unroll
  for (int i = 0; i < 32; i += 8)
    tile[ty + i][tx] = f2bf(W[(size_t)(by + ty + i) * DM + bx + tx]);
  __syncthreads();
  #pragma unroll
  for (int i = 0; i < 32; i += 8)
    Wt[(size_t)(bx + ty + i) * DM + by + tx] = tile[tx][ty + i];
}

// ---------------- legacy 128x128 GEMM (kept for proj + fallback) ----------
// Y = A[M,K] * Bt[N,K]^T, bf16 in, fp32 acc. Output modes:
// 0: fp32 [M,N]
// 1: bf16 [B,H,T,DH]                         (Q — normal head layout)
// 3: bf16 [B,H,T,DH], dh' = dh ^ ((t&7)<<3)  (K — XOR-swizzled for dense LDS)
// 2: bf16 [B,H,t/64, DH, 64], t' = (t&63) ^ ((dh&7)<<3)  (V^T 64-key panels)
__global__ __launch_bounds__(256)
void gemm_bt(const u16* __restrict__ A, const u16* __restrict__ Bt_base,
             void* __restrict__ C0, u16* __restrict__ Ck, u16* __restrict__ Cv,
             int mode0){
  __shared__ u16 As[2][128][32];
  __shared__ u16 Bs[2][128][32];
  const int z = blockIdx.z;
  const u16* Bt = Bt_base + (size_t)z * DM * DM;
  void* C = (z == 0) ? C0 : (z == 1) ? (void*)Ck : (void*)Cv;
  const int mode = (z == 0) ? mode0 : (z == 1) ? 3 : 2;

  const int tid = threadIdx.x;
  const int wave = tid >> 6, lane = tid & 63;
  const int wm = wave & 1, wn = wave >> 1;
  const int row16 = lane & 15, quad = lane >> 4;
  const int m0 = blockIdx.x * 128, n0 = blockIdx.y * 128;

  const f32x4 zero = {0.f, 0.f, 0.f, 0.f};
  f32x4 acc[4][4];
  #pragma unroll
  for (int i = 0; i < 4; i++)
    #pragma unroll
    for (int j = 0; j < 4; j++) acc[i][j] = zero;

  const int srow = lane >> 2;           // 0..15 within 16-row chunk
  const int scol = (lane & 3) * 8;      // u16 units, 16B per lane

  for (int k0 = 0; k0 < DM; k0 += 64){
    #pragma unroll
    for (int c = 0; c < 2; c++){
      const int rbase = wave * 32 + c * 16;
      const u16* pa = A  + (size_t)(m0 + rbase + srow) * DM + k0 + scol;
      const u16* pb = Bt + (size_t)(n0 + rbase + srow) * DM + k0 + scol;
      gl_lds16(pa,      &As[0][rbase][0]);
      gl_lds16(pa + 32, &As[1][rbase][0]);
      gl_lds16(pb,      &Bs[0][rbase][0]);
      gl_lds16(pb + 32, &Bs[1][rbase][0]);
    }
    __syncthreads();
    #pragma unroll
    for (int buf = 0; buf < 2; buf++){
      bf16x8 af[4], bfr[4];
      #pragma unroll
      for (int mt = 0; mt < 4; mt++)
        af[mt] = *(const bf16x8*)&As[buf][wm * 64 + mt * 16 + row16][quad * 8];
      #pragma unroll
      for (int nt = 0; nt < 4; nt++)
        bfr[nt] = *(const bf16x8*)&Bs[buf][wn * 64 + nt * 16 + row16][quad * 8];
      #pragma unroll
      for (int mt = 0; mt < 4; mt++)
        #pragma unroll
        for (int nt = 0; nt < 4; nt++)
          acc[mt][nt] = __builtin_amdgcn_mfma_f32_16x16x32_bf16(af[mt], bfr[nt], acc[mt][nt], 0, 0, 0);
    }
    __syncthreads();
  }

  #pragma unroll
  for (int mt = 0; mt < 4; mt++){
    #pragma unroll
    for (int nt = 0; nt < 4; nt++){
      #pragma unroll
      for (int r = 0; r < 4; r++){
        const int m = m0 + wm * 64 + mt * 16 + quad * 4 + r;
        const int n = n0 + wn * 64 + nt * 16 + row16;
        const int b = m >> 11, t = m & (TT - 1);
        const int hh = n >> 7, dh = n & (DH - 1);
        if (mode == 1){
          ((u16*)C)[(((size_t)(b * NH + hh) * TT + t) * DH) + dh] = f2bf(acc[mt][nt][r]);
        } else if (mode == 3){
          const int dhs = dh ^ ((t & 7) << 3);
          ((u16*)C)[(((size_t)(b * NH + hh) * TT + t) * DH) + dhs] = f2bf(acc[mt][nt][r]);
        } else if (mode == 2){
          const int ts = (t & 63) ^ ((dh & 7) << 3);
          ((u16*)C)[(((size_t)(b * NH + hh) * 32 + (t >> 6)) * 8192) + dh * 64 + ts] = f2bf(acc[mt][nt][r]);
        } else {
          ((float*)C)[(size_t)m * DM + n] = acc[mt][nt][r];
        }
      }
    }
  }
}

// ---------------- 256x256 8-phase GEMM (T3+T4+T5) for the QKV dispatch ----
// 512 thr = 8 waves (2M x 4N), per-wave 128x64 out. BK=64 split into two
// k-halves; LDS is k-half-major [buf][kh][256 rows][32 k] so a staged
// half-tile is 16KB contiguous (global_load_lds-linear) and phases 1-2 read
// only kh0, phases 3-4 only kh1. Prefetch of tile t+2's kh0 is issued in
// phase 3 (after the phase-2 end barrier => all kh0 reads complete) into the
// region just freed: race-free without draining vmcnt. vmcnt(4) once per
// K-tile leaves the 2 newest half-tiles (t+2.kh0 A,B) in flight.
#define SB() do{ asm volatile("" ::: "memory"); \
                 __builtin_amdgcn_s_barrier();  \
                 asm volatile("" ::: "memory"); }while(0)
#define WAITV4 asm volatile("s_waitcnt vmcnt(4)" ::: "memory")
#define WAITV0 asm volatile("s_waitcnt vmcnt(0)" ::: "memory")
#define NOPW do{}while(0)

#define STAGE_A(bf, kh, koff) do{ \
  gl_lds16(aS + (koff),                    &As[bf][kh][wave * 16][0]); \
  gl_lds16(aS + (size_t)128 * DM + (koff), &As[bf][kh][128 + wave * 16][0]); }while(0)
#define STAGE_B(bf, kh, koff) do{ \
  gl_lds16(bS + (koff),                    &Bs[bf][kh][wave * 16][0]); \
  gl_lds16(bS + (size_t)128 * DM + (koff), &Bs[bf][kh][128 + wave * 16][0]); }while(0)

// one phase: [8 or 4 ds_read_b128][stage][wait][barrier][setprio+16 MFMA][barrier]
#define PHASE(bufc, kh, fh, STAGE, WAIT) do{ \
  bf16x8 af[4]; \
  _Pragma("unroll") \
  for (int i = 0; i < 4; i++) \
    af[i] = *(const bf16x8*)&As[bufc][kh][wm * 128 + (fh) * 64 + i * 16 + row16][quad * 8]; \
  if ((fh) == 0){ \
    _Pragma("unroll") \
    for (int j = 0; j < 4; j++) \
      bk[j] = *(const bf16x8*)&Bs[bufc][kh][wn * 64 + j * 16 + row16][quad * 8]; \
  } \
  STAGE; WAIT; \
  SB(); \
  __builtin_amdgcn_s_setprio(1); \
  _Pragma("unroll") \
  for (int i = 0; i < 4; i++) \
    _Pragma("unroll") \
    for (int j = 0; j < 4; j++) \
      acc[(fh) * 4 + i][j] = __builtin_amdgcn_mfma_f32_16x16x32_bf16(af[i], bk[j], acc[(fh) * 4 + i][j], 0, 0, 0); \
  __builtin_amdgcn_s_setprio(0); \
  SB(); \
}while(0)

__global__ __launch_bounds__(512, 2)
void gemm256(const u16* __restrict__ A, const u16* __restrict__ Bt_base,
             void* __restrict__ C0, u16* __restrict__ Ck, u16* __restrict__ Cv,
             int mode0){
  __shared__ u16 As[2][2][256][32];   // 64KB: [buf][khalf][row][k]
  __shared__ u16 Bs[2][2][256][32];   // 64KB
  const int z = blockIdx.z;
  const u16* Bt = Bt_base + (size_t)z * DM * DM;
  void* C = (z == 0) ? C0 : (z == 1) ? (void*)Ck : (void*)Cv;
  const int mode = (z == 0) ? mode0 : (z == 1) ? 3 : 2;

  const int tid = threadIdx.x;
  const int wave = tid >> 6, lane = tid & 63;
  const int wm = wave >> 2, wn = wave & 3;          // 2M x 4N wave grid
  const int row16 = lane & 15, quad = lane >> 4;
  const int m0 = blockIdx.x * 256, n0 = blockIdx.y * 256;

  // staging: half-tile = 256 rows x 32 k = 16KB = 2 gl_lds slots/wave.
  // slot s covers rows [s*128 + wave*16, +16); lane -> (row lane>>2, 16B chunk lane&3)
  const int srow = wave * 16 + (lane >> 2);
  const int scol = (lane & 3) * 8;
  const u16* aS = A  + (size_t)(m0 + srow) * DM + scol;
  const u16* bS = Bt + (size_t)(n0 + srow) * DM + scol;

  const f32x4 zero = {0.f, 0.f, 0.f, 0.f};
  f32x4 acc[8][4];
  #pragma unroll
  for (int i = 0; i < 8; i++)
    #pragma unroll
    for (int j = 0; j < 4; j++) acc[i][j] = zero;
  bf16x8 bk[4];

  // prologue: tile0 (both k-halves) + tile1.kh0 => 6 units, 12 loads/wave.
  // vmcnt(4): all of tile0 landed; tile1.kh0 may float.
  STAGE_A(0, 0, 0);  STAGE_B(0, 0, 0);
  STAGE_A(0, 1, 32); STAGE_B(0, 1, 32);
  STAGE_A(1, 0, 64); STAGE_B(1, 0, 64);
  WAITV4;
  SB();

  // steady state: tiles 0..29
  #pragma unroll 2
  for (int t = 0; t < 30; ++t){
    const int buf = t & 1, nb = buf ^ 1;
    const int k1 = (t + 1) * 64 + 32;   // next tile, kh1
    const int k2 = (t + 2) * 64;        // tile after next, kh0
    PHASE(buf, 0, 0, STAGE_A(nb, 1, k1), NOPW);
    PHASE(buf, 0, 1, STAGE_B(nb, 1, k1), NOPW);
    PHASE(buf, 1, 0, STAGE_A(buf, 0, k2), NOPW);
    PHASE(buf, 1, 1, STAGE_B(buf, 0, k2), WAITV4);
  }
  // t = 30 (buf 0): stage tile31.kh1 only; drain before last tile
  PHASE(0, 0, 0, STAGE_A(1, 1, 31 * 64 + 32), NOPW);
  PHASE(0, 0, 1, STAGE_B(1, 1, 31 * 64 + 32), NOPW);
  PHASE(0, 1, 0, NOPW, NOPW);
  PHASE(0, 1, 1, NOPW, WAITV0);
  // t = 31 (buf 1): compute only
  PHASE(1, 0, 0, NOPW, NOPW);
  PHASE(1, 0, 1, NOPW, NOPW);
  PHASE(1, 1, 0, NOPW, NOPW);
  PHASE(1, 1, 1, NOPW, NOPW);

  // epilogue: C/D layout row = quad*4+reg, col = lane&15
  #pragma unroll
  for (int mt = 0; mt < 8; mt++){
    #pragma unroll
    for (int nt = 0; nt < 4; nt++){
      #pragma unroll
      for (int r = 0; r < 4; r++){
        const int m = m0 + wm * 128 + mt * 16 + quad * 4 + r;
        const int n = n0 + wn * 64 + nt * 16 + row16;
        const int b = m >> 11, t = m & (TT - 1);
        const int hh = n >> 7, dh = n & (DH - 1);
        if (mode == 1){
          ((u16*)C)[(((size_t)(b * NH + hh) * TT + t) * DH) + dh] = f2bf(acc[mt][nt][r]);
        } else if (mode == 3){
          const int dhs = dh ^ ((t & 7) << 3);
          ((u16*)C)[(((size_t)(b * NH + hh) * TT + t) * DH) + dhs] = f2bf(acc[mt][nt][r]);
        } else if (mode == 2){
          const int ts = (t & 63) ^ ((dh & 7) << 3);
          ((u16*)C)[(((size_t)(b * NH + hh) * 32 + (t >> 6)) * 8192) + dh * 64 + ts] = f2bf(acc[mt][nt][r]);
        } else {
          ((float*)C)[(size_t)m * DM + n] = acc[mt][nt][r];
        }
      }
    }
  }
}

// ---------------- fused RoPE on q (normal) AND k (swizzled storage) --------
__global__ __launch_bounds__(256)
void rope2(u16* __restrict__ qb, u16* __restrict__ kb, const int* __restrict__ posp){
  const int idx = blockIdx.x * 256 + threadIdx.x;   // one per (row, pair-slot)
  const int pair = idx & 63;
  const int row = idx >> 6;                          // b*H*T + h*T + t
  const int t = row & (TT - 1);
  int p0 = *posp; if (p0 < 0) p0 = 0;
  const float tf = (float)(p0 + t);
  const size_t base = (size_t)row * DH;
  // q: storage pair == logical pair
  {
    const float inv = expf(-(float)pair * (9.2103403719761836f / 64.f));
    float sn, cs; sincosf(tf * inv, &sn, &cs);
    const float q1 = bf2f(qb[base + pair]);
    const float q2 = bf2f(qb[base + 64 + pair]);
    qb[base + pair]      = f2bf(q1 * cs - q2 * sn);
    qb[base + 64 + pair] = f2bf(q1 * sn + q2 * cs);
  }
  // k: storage slot `pair` holds logical dh = pair ^ ((t&7)<<3)
  {
    const int pl = pair ^ ((t & 7) << 3);
    const float inv = expf(-(float)pl * (9.2103403719761836f / 64.f));
    float sn, cs; sincosf(tf * inv, &sn, &cs);
    const float k1 = bf2f(kb[base + pair]);
    const float k2 = bf2f(kb[base + 64 + pair]);
    kb[base + pair]      = f2bf(k1 * cs - k2 * sn);
    kb[base + 64 + pair] = f2bf(k1 * sn + k2 * cs);
  }
}

// ---------------- causal flash attention v6: async-DMA staging -------------
// 64 q-rows/block, 1024 blocks, fixed-m softmax (R7-proven). K and V^T are
// stored XOR-swizzled in global (gemm modes 3/2), so LDS tiles are DENSE and
// staged with global_load_lds. Fragment reads XOR the column.
template<bool MASK>
__device__ __forceinline__ void attn_tile(
    int kt0, int qbase, int wave, int row16, int quad,
    const bf16x8 (&qf)[4],
    u16 (&k_s)[64][128], u16 (&vt_s)[128][64], u16 (&p_s)[4][16][72],
    f32x4 (&o_acc)[8], float (&l_acc)[4])
{
  const float scale = 0.08838834764831845f;  // 1/sqrt(128)
  const f32x4 zero = {0.f, 0.f, 0.f, 0.f};
  const int fx = (row16 & 7) << 3;           // XOR de-swizzle
  f32x4 s_acc[4];
  #pragma unroll
  for (int nt = 0; nt < 4; nt++) s_acc[nt] = zero;
  #pragma unroll
  for (int st = 0; st < 4; st++)
    #pragma unroll
    for (int nt = 0; nt < 4; nt++){
      const bf16x8 kf = *(const bf16x8*)&k_s[nt * 16 + row16][(st * 32 + quad * 8) ^ fx];
      s_acc[nt] = __builtin_amdgcn_mfma_f32_16x16x32_bf16(qf[st], kf, s_acc[nt], 0, 0, 0);
    }
  #pragma unroll
  for (int r = 0; r < 4; r++){
    float ps = 0.f;
    #pragma unroll
    for (int nt = 0; nt < 4; nt++){
      float p = __expf(s_acc[nt][r] * scale);
      if (MASK){
        const int qr = qbase + quad * 4 + r;
        if (kt0 + nt * 16 + row16 > qr) p = 0.f;
      }
      ps += p;
      p_s[wave][quad * 4 + r][nt * 16 + row16] = f2bf(p);
    }
    l_acc[r] += ps;
  }
  asm volatile("" ::: "memory");  // p_s wave-private; DS in-order per wave

  #pragma unroll
  for (int kk = 0; kk < 2; kk++){
    const bf16x8 pf = *(const bf16x8*)&p_s[wave][row16][kk * 32 + quad * 8];
    #pragma unroll
    for (int nd = 0; nd < 8; nd++){
      const bf16x8 vb = *(const bf16x8*)&vt_s[nd * 16 + row16][(kk * 32 + quad * 8) ^ fx];
      o_acc[nd] = __builtin_amdgcn_mfma_f32_16x16x32_bf16(pf, vb, o_acc[nd], 0, 0, 0);
    }
  }
}

__global__ __launch_bounds__(256)
void attn_fwd(const u16* __restrict__ q, const u16* __restrict__ k,
              const u16* __restrict__ vtg, u16* __restrict__ ctx){
  __shared__ u16 k_s[64][128];     // dense [key][dh'], DMA-staged
  __shared__ u16 vt_s[128][64];    // dense [dh][t'], DMA-staged
  __shared__ u16 p_s[4][16][72];   // per-wave P [q][key]
  const int tid = threadIdx.x;
  const int wave = tid >> 6, lane = tid & 63;
  const int row16 = lane & 15, quad = lane >> 4;
  const int bh = blockIdx.y;
  const int q0 = (31 - blockIdx.x) * 64;   // heavy blocks dispatch first
  const int qbase = q0 + wave * 16;
  const size_t bho = (size_t)bh * TT * DH;

  bf16x8 qf[4];
  {
    const u16* qp = q + bho + (size_t)(qbase + row16) * DH + quad * 8;
    #pragma unroll
    for (int st = 0; st < 4; st++) qf[st] = *(const bf16x8*)(qp + st * 32);
  }

  float l_acc[4] = {0.f, 0.f, 0.f, 0.f};
  const f32x4 zero = {0.f, 0.f, 0.f, 0.f};
  f32x4 o_acc[8];
  #pragma unroll
  for (int i = 0; i < 8; i++) o_acc[i] = zero;

  // DMA lane maps: K 1KB = 4 rows x 256B; V 1KB = 8 rows x 128B
  const int kl_r = lane >> 4, kl_c = (lane & 15) * 8;
  const int vl_r = lane >> 3, vl_c = (lane & 7) * 8;

  for (int kt0 = 0; kt0 < q0 + 64; kt0 += 64){
    // K: wave stages rows [16w, 16w+16) via 4 async 1KB DMAs
    #pragma unroll
    for (int i = 0; i < 4; i++){
      const int rb = wave * 16 + i * 4;
      gl_lds16(k + bho + (size_t)(kt0 + rb + kl_r) * DH + kl_c, &k_s[rb][0]);
    }
    // V: panel (kt0/64) is 16KB contiguous; wave stages dh [32w, 32w+32)
    const u16* vpan = vtg + ((size_t)bh * 32 + (kt0 >> 6)) * 8192;
    #pragma unroll
    for (int i = 0; i < 4; i++){
      const int rb = wave * 32 + i * 8;
      gl_lds16(vpan + (size_t)(rb + vl_r) * 64 + vl_c, &vt_s[rb][0]);
    }
    __syncthreads();   // compiler drains vmcnt(0) -> DMA complete

    if (kt0 < q0)
      attn_tile<false>(kt0, qbase, wave, row16, quad, qf, k_s, vt_s, p_s, o_acc, l_acc);
    else
      attn_tile<true >(kt0, qbase, wave, row16, quad, qf, k_s, vt_s, p_s, o_acc, l_acc);

    __syncthreads();   // protect restage
  }

  #pragma unroll
  for (int r = 0; r < 4; r++){
    #pragma unroll
    for (int off = 1; off < 16; off <<= 1) l_acc[r] += __shfl_xor(l_acc[r], off, 64);
  }

  const int b = bh >> 4, h = bh & 15;
  #pragma unroll
  for (int nd = 0; nd < 8; nd++){
    #pragma unroll
    for (int r = 0; r < 4; r++){
      const int qr = qbase + quad * 4 + r;
      const size_t off = ((size_t)b * TT + qr) * DM + h * DH + nd * 16 + row16;
      ctx[off] = f2bf(o_acc[nd][r] / l_acc[r]);
    }
  }
}

extern "C" void kernel_launch(void* const* d_in, const int* in_sizes, int n_in,
                              void* d_out, int out_size, void* d_ws, size_t ws_size,
                              hipStream_t stream){
  const float* x  = (const float*)d_in[0];   // fp32 per reference
  const float* wq = (const float*)d_in[1];
  const float* wk = (const float*)d_in[2];
  const float* wv = (const float*)d_in[3];
  const float* wo = (const float*)d_in[4];
  const int* pos  = (const int*)d_in[5];

  char* ws = (char*)d_ws;
  const dim3 tg(64, 64), tb(32, 8);

  if (ws_size >= 92274688ull){
    // fused path: xb 16MB | wt3 25.2MB | qb 16 | kb 16 | vtg 16 = 92.3MB
    u16* xb  = (u16*)ws;                  u16* cb = xb;
    u16* wt3 = (u16*)(ws + 16777216);
    u16* qb  = (u16*)(ws + 41943040);
    u16* kb  = (u16*)(ws + 58720256);
    u16* vtg = (u16*)(ws + 75497472);

    cvt_f32_bf16<<<8192, 256, 0, stream>>>(x, xb, 2097152);
    transpose3<<<dim3(64, 64, 3), tb, 0, stream>>>(wq, wk, wv, wt3);
    gemm256<<<dim3(16, 8, 3), 512, 0, stream>>>(xb, wt3, qb, kb, vtg, 1);
    transpose2048<<<tg, tb, 0, stream>>>(wo, wt3);   // slot0 (wq^T) dead; hoisted
    rope2<<<16384, 256, 0, stream>>>(qb, kb, pos);
    attn_fwd<<<dim3(32, 32), 256, 0, stream>>>(qb, kb, vtg, cb);
    gemm_bt<<<dim3(32, 16, 1), 256, 0, stream>>>(cb, wt3, d_out, 0, 0, 0);
  } else {
    // fallback (75.5MB): xb/cb 16 | wt 8 | qb 16 | kb 16 | vtg 16
    u16* xb  = (u16*)ws;                  u16* cb = xb;
    u16* wt  = (u16*)(ws + 16777216);
    u16* qb  = (u16*)(ws + 25165824);
    u16* kb  = (u16*)(ws + 41943040);
    u16* vtg = (u16*)(ws + 58720256);

    cvt_f32_bf16<<<8192, 256, 0, stream>>>(x, xb, 2097152);
    transpose2048<<<tg, tb, 0, stream>>>(wq, wt);
    gemm_bt<<<dim3(32, 16, 1), 256, 0, stream>>>(xb, wt, qb, 0, 0, 1);
    transpose2048<<<tg, tb, 0, stream>>>(wk, wt);
    gemm_bt<<<dim3(32, 16, 1), 256, 0, stream>>>(xb, wt, kb, 0, 0, 3);
    transpose2048<<<tg, tb, 0, stream>>>(wv, wt);
    gemm_bt<<<dim3(32, 16, 1), 256, 0, stream>>>(xb, wt, vtg, 0, 0, 2);
    rope2<<<16384, 256, 0, stream>>>(qb, kb, pos);
    attn_fwd<<<dim3(32, 32), 256, 0, stream>>>(qb, kb, vtg, cb);
    transpose2048<<<tg, tb, 0, stream>>>(wo, wt);
    gemm_bt<<<dim3(32, 16, 1), 256, 0, stream>>>(cb, wt, d_out, 0, 0, 0);
  }
}

// Round 2
// 475.887 us; speedup vs baseline: 1.0193x; 1.0193x over previous
//
#include <hip/hip_runtime.h>
#include <hip/hip_bf16.h>
#include <math.h>

#define NH 16
#define DH 128
#define DM 2048
#define BB 2
#define TT 2048

typedef unsigned short u16;
typedef __attribute__((ext_vector_type(8))) __bf16 bf16x8;
typedef __attribute__((ext_vector_type(8))) u16 u16x8;
typedef __attribute__((ext_vector_type(4))) u16 u16x4;
typedef __attribute__((ext_vector_type(4))) float f32x4;

__device__ __forceinline__ float bf2f(u16 a){
  union { unsigned u; float f; } v; v.u = ((unsigned)a) << 16; return v.f;
}
__device__ __forceinline__ u16 f2bf(float f){
  union { float f; unsigned u; } v; v.f = f;
  unsigned r = v.u + 0x7fffu + ((v.u >> 16) & 1u);  // RNE
  return (u16)(r >> 16);
}

// async global->LDS, 16B per lane. LDS dest = wave-uniform base + lane*16.
typedef const __attribute__((address_space(1))) unsigned int* gas_p;
typedef __attribute__((address_space(3))) unsigned int* las_p;
__device__ __forceinline__ void gl_lds16(const u16* g, u16* lds_uniform_base){
  __builtin_amdgcn_global_load_lds((gas_p)(const void*)g,
                                   (las_p)(void*)lds_uniform_base, 16, 0, 0);
}

#define SB() do{ asm volatile("" ::: "memory"); \
                 __builtin_amdgcn_s_barrier();  \
                 asm volatile("" ::: "memory"); }while(0)
#define WAITV4 asm volatile("s_waitcnt vmcnt(4)" ::: "memory")
#define WAITV0 asm volatile("s_waitcnt vmcnt(0)" ::: "memory")

// ---------------- fp32 -> bf16 elementwise, 4/thread ----------------
__global__ __launch_bounds__(256)
void cvt_f32_bf16(const float* __restrict__ src, u16* __restrict__ dst, int n4){
  const int i = blockIdx.x * 256 + threadIdx.x;
  if (i >= n4) return;
  const f32x4 v = *(const f32x4*)(src + (size_t)i * 4);
  u16x4 o;
  #pragma unroll
  for (int j = 0; j < 4; j++) o[j] = f2bf(v[j]);
  *(u16x4*)(dst + (size_t)i * 4) = o;
}

// ---------------- W fp32 [K,N] -> Wt bf16 [N,K] (single) ----------------
__global__ __launch_bounds__(256)
void transpose2048(const float* __restrict__ W, u16* __restrict__ Wt){
  __shared__ u16 tile[32][33];
  const int tx = threadIdx.x, ty = threadIdx.y;
  const int bx = blockIdx.x * 32, by = blockIdx.y * 32;
  #pragma unroll
  for (int i = 0; i < 32; i += 8)
    tile[ty + i][tx] = f2bf(W[(size_t)(by + ty + i) * DM + bx + tx]);
  __syncthreads();
  #pragma unroll
  for (int i = 0; i < 32; i += 8)
    Wt[(size_t)(bx + ty + i) * DM + by + tx] = tile[tx][ty + i];
}

// ---------------- 3 weights fused via z ----------------
__global__ __launch_bounds__(256)
void transpose3(const float* __restrict__ w0, const float* __restrict__ w1,
                const float* __restrict__ w2, u16* __restrict__ dst){
  __shared__ u16 tile[32][33];
  const int z = blockIdx.z;
  const float* W = (z == 0) ? w0 : (z == 1) ? w1 : w2;
  u16* Wt = dst + (size_t)z * DM * DM;
  const int tx = threadIdx.x, ty = threadIdx.y;
  const int bx = blockIdx.x * 32, by = blockIdx.y * 32;
  #pragma unroll
  for (int i = 0; i < 32; i += 8)
    tile[ty + i][tx] = f2bf(W[(size_t)(by + ty + i) * DM + bx + tx]);
  __syncthreads();
  #pragma unroll
  for (int i = 0; i < 32; i += 8)
    Wt[(size_t)(bx + ty + i) * DM + by + tx] = tile[tx][ty + i];
}

// ---------------- legacy 128x128 GEMM (fallback path only) ----------
__global__ __launch_bounds__(256)
void gemm_bt(const u16* __restrict__ A, const u16* __restrict__ Bt_base,
             void* __restrict__ C0, u16* __restrict__ Ck, u16* __restrict__ Cv,
             int mode0){
  __shared__ u16 As[2][128][32];
  __shared__ u16 Bs[2][128][32];
  const int z = blockIdx.z;
  const u16* Bt = Bt_base + (size_t)z * DM * DM;
  void* C = (z == 0) ? C0 : (z == 1) ? (void*)Ck : (void*)Cv;
  const int mode = (z == 0) ? mode0 : (z == 1) ? 3 : 2;

  const int tid = threadIdx.x;
  const int wave = tid >> 6, lane = tid & 63;
  const int wm = wave & 1, wn = wave >> 1;
  const int row16 = lane & 15, quad = lane >> 4;
  const int m0 = blockIdx.x * 128, n0 = blockIdx.y * 128;

  const f32x4 zero = {0.f, 0.f, 0.f, 0.f};
  f32x4 acc[4][4];
  #pragma unroll
  for (int i = 0; i < 4; i++)
    #pragma unroll
    for (int j = 0; j < 4; j++) acc[i][j] = zero;

  const int srow = lane >> 2;           // 0..15 within 16-row chunk
  const int scol = (lane & 3) * 8;      // u16 units, 16B per lane

  for (int k0 = 0; k0 < DM; k0 += 64){
    #pragma unroll
    for (int c = 0; c < 2; c++){
      const int rbase = wave * 32 + c * 16;
      const u16* pa = A  + (size_t)(m0 + rbase + srow) * DM + k0 + scol;
      const u16* pb = Bt + (size_t)(n0 + rbase + srow) * DM + k0 + scol;
      gl_lds16(pa,      &As[0][rbase][0]);
      gl_lds16(pa + 32, &As[1][rbase][0]);
      gl_lds16(pb,      &Bs[0][rbase][0]);
      gl_lds16(pb + 32, &Bs[1][rbase][0]);
    }
    __syncthreads();
    #pragma unroll
    for (int buf = 0; buf < 2; buf++){
      bf16x8 af[4], bfr[4];
      #pragma unroll
      for (int mt = 0; mt < 4; mt++)
        af[mt] = *(const bf16x8*)&As[buf][wm * 64 + mt * 16 + row16][quad * 8];
      #pragma unroll
      for (int nt = 0; nt < 4; nt++)
        bfr[nt] = *(const bf16x8*)&Bs[buf][wn * 64 + nt * 16 + row16][quad * 8];
      #pragma unroll
      for (int mt = 0; mt < 4; mt++)
        #pragma unroll
        for (int nt = 0; nt < 4; nt++)
          acc[mt][nt] = __builtin_amdgcn_mfma_f32_16x16x32_bf16(af[mt], bfr[nt], acc[mt][nt], 0, 0, 0);
    }
    __syncthreads();
  }

  #pragma unroll
  for (int mt = 0; mt < 4; mt++){
    #pragma unroll
    for (int nt = 0; nt < 4; nt++){
      #pragma unroll
      for (int r = 0; r < 4; r++){
        const int m = m0 + wm * 64 + mt * 16 + quad * 4 + r;
        const int n = n0 + wn * 64 + nt * 16 + row16;
        const int b = m >> 11, t = m & (TT - 1);
        const int hh = n >> 7, dh = n & (DH - 1);
        if (mode == 1){
          ((u16*)C)[(((size_t)(b * NH + hh) * TT + t) * DH) + dh] = f2bf(acc[mt][nt][r]);
        } else if (mode == 3){
          const int dhs = dh ^ ((t & 7) << 3);
          ((u16*)C)[(((size_t)(b * NH + hh) * TT + t) * DH) + dhs] = f2bf(acc[mt][nt][r]);
        } else if (mode == 2){
          const int ts = (t & 63) ^ ((dh & 7) << 3);
          ((u16*)C)[(((size_t)(b * NH + hh) * 32 + (t >> 6)) * 8192) + dh * 64 + ts] = f2bf(acc[mt][nt][r]);
        } else {
          ((float*)C)[(size_t)m * DM + n] = acc[mt][nt][r];
        }
      }
    }
  }
}

// ---------------- 128x128 GEMM v2: k-half counted-vmcnt + swizzle ----------
// Same geometry/occupancy as gemm_bt (32KB LDS, ~3 blocks/CU, 1536-block QKV
// grid = 2 exact rounds). Two changes vs m97 structure:
// (1) k-half pipeline: each 32-wide k-half is staged ONE PHASE ahead into the
//     half-buffer just freed; per-phase s_waitcnt vmcnt(4) (never 0 in loop)
//     gives every DMA a full phase (~frag-reads + 16 MFMA x 3 blocks/CU) of
//     cover instead of gemm_bt's zero-cover vmcnt(0) drain.
// (2) bank-conflict swizzle: 64B LDS rows give slot = 4*(row&1)+quad => 4-way
//     conflict on ds_read_b128. Store chunk c at c ^ ((row>>1)&3) by
//     pre-swizzling the per-lane GLOBAL source (LDS dest stays linear for
//     global_load_lds); reads XOR the same term => uniform 8 lanes/slot.
__global__ __launch_bounds__(256)
void gemm_bt2(const u16* __restrict__ A, const u16* __restrict__ Bt_base,
              void* __restrict__ C0, u16* __restrict__ Ck, u16* __restrict__ Cv,
              int mode0){
  __shared__ u16 As[2][128][32];   // [khalf][row][k32], swizzled chunks
  __shared__ u16 Bs[2][128][32];
  const int z = blockIdx.z;
  const u16* Bt = Bt_base + (size_t)z * DM * DM;
  void* C = (z == 0) ? C0 : (z == 1) ? (void*)Ck : (void*)Cv;
  const int mode = (z == 0) ? mode0 : (z == 1) ? 3 : 2;

  const int tid = threadIdx.x;
  const int wave = tid >> 6, lane = tid & 63;
  const int wm = wave & 1, wn = wave >> 1;
  const int row16 = lane & 15, quad = lane >> 4;
  const int m0 = blockIdx.x * 128, n0 = blockIdx.y * 128;

  const f32x4 zero = {0.f, 0.f, 0.f, 0.f};
  f32x4 acc[4][4];
  #pragma unroll
  for (int i = 0; i < 4; i++)
    #pragma unroll
    for (int j = 0; j < 4; j++) acc[i][j] = zero;

  // staging lane map: unit = 16 rows x 64B; source chunk pre-swizzled so the
  // linear LDS fill lands chunk c of row r at c ^ ((r>>1)&3).
  const int srow = lane >> 2;                                   // 0..15
  const int scol = ((lane & 3) ^ ((lane >> 3) & 3)) * 8;        // u16 units
  const u16* aBase = A  + (size_t)(m0 + wave * 32 + srow) * DM + scol;
  const u16* bBase = Bt + (size_t)(n0 + wave * 32 + srow) * DM + scol;

  // fragment-read column (undoes the swizzle; row&7 == row16&7 here)
  const int fcol = (quad ^ ((row16 >> 1) & 3)) * 8;

  // stage one k-half of A and B: 4 async 1KB DMAs per wave
  #define STAGE2(kh, kc) do{ \
    const int ko = (kc) + (kh) * 32; \
    gl_lds16(aBase + ko,                     &As[kh][wave * 32][0]); \
    gl_lds16(aBase + ko + (size_t)16 * DM,   &As[kh][wave * 32 + 16][0]); \
    gl_lds16(bBase + ko,                     &Bs[kh][wave * 32][0]); \
    gl_lds16(bBase + ko + (size_t)16 * DM,   &Bs[kh][wave * 32 + 16][0]); \
  }while(0)

  #define PHASE2(kh) do{ \
    bf16x8 af[4], bk[4]; \
    _Pragma("unroll") \
    for (int mt = 0; mt < 4; mt++) \
      af[mt] = *(const bf16x8*)&As[kh][wm * 64 + mt * 16 + row16][fcol]; \
    _Pragma("unroll") \
    for (int nt = 0; nt < 4; nt++) \
      bk[nt] = *(const bf16x8*)&Bs[kh][wn * 64 + nt * 16 + row16][fcol]; \
    __builtin_amdgcn_s_setprio(1); \
    _Pragma("unroll") \
    for (int mt = 0; mt < 4; mt++) \
      _Pragma("unroll") \
      for (int nt = 0; nt < 4; nt++) \
        acc[mt][nt] = __builtin_amdgcn_mfma_f32_16x16x32_bf16(af[mt], bk[nt], acc[mt][nt], 0, 0, 0); \
    __builtin_amdgcn_s_setprio(0); \
  }while(0)

  // prologue: kh0 of tile 0 in flight (4 outstanding)
  STAGE2(0, 0);

  // steady state. Invariant at loop top: outstanding = kh0(t) [4 loads].
  // Each WAITV4 retires everything except the 4 just-issued loads.
  for (int t = 0; t < 31; ++t){
    const int kc = t * 64;
    STAGE2(1, kc);            // kh1(t) -> 8 outstanding
    WAITV4;                   // kh0(t) landed
    SB();
    PHASE2(0);
    SB();                     // all waves done reading kh0
    STAGE2(0, kc + 64);       // kh0(t+1) -> 8 outstanding
    WAITV4;                   // kh1(t) landed
    SB();
    PHASE2(1);
    SB();                     // all waves done reading kh1
  }
  // peeled tail: t = 31 (no kh0(32) prefetch -> no OOB)
  STAGE2(1, 31 * 64);
  WAITV4; SB();
  PHASE2(0);
  SB();
  WAITV0; SB();
  PHASE2(1);

  #undef STAGE2
  #undef PHASE2

  // epilogue: C/D layout row = quad*4+reg, col = lane&15
  #pragma unroll
  for (int mt = 0; mt < 4; mt++){
    #pragma unroll
    for (int nt = 0; nt < 4; nt++){
      #pragma unroll
      for (int r = 0; r < 4; r++){
        const int m = m0 + wm * 64 + mt * 16 + quad * 4 + r;
        const int n = n0 + wn * 64 + nt * 16 + row16;
        const int b = m >> 11, t = m & (TT - 1);
        const int hh = n >> 7, dh = n & (DH - 1);
        if (mode == 1){
          ((u16*)C)[(((size_t)(b * NH + hh) * TT + t) * DH) + dh] = f2bf(acc[mt][nt][r]);
        } else if (mode == 3){
          const int dhs = dh ^ ((t & 7) << 3);
          ((u16*)C)[(((size_t)(b * NH + hh) * TT + t) * DH) + dhs] = f2bf(acc[mt][nt][r]);
        } else if (mode == 2){
          const int ts = (t & 63) ^ ((dh & 7) << 3);
          ((u16*)C)[(((size_t)(b * NH + hh) * 32 + (t >> 6)) * 8192) + dh * 64 + ts] = f2bf(acc[mt][nt][r]);
        } else {
          ((float*)C)[(size_t)m * DM + n] = acc[mt][nt][r];
        }
      }
    }
  }
}

// ---------------- fused RoPE on q (normal) AND k (swizzled storage) --------
__global__ __launch_bounds__(256)
void rope2(u16* __restrict__ qb, u16* __restrict__ kb, const int* __restrict__ posp){
  const int idx = blockIdx.x * 256 + threadIdx.x;   // one per (row, pair-slot)
  const int pair = idx & 63;
  const int row = idx >> 6;                          // b*H*T + h*T + t
  const int t = row & (TT - 1);
  int p0 = *posp; if (p0 < 0) p0 = 0;
  const float tf = (float)(p0 + t);
  const size_t base = (size_t)row * DH;
  // q: storage pair == logical pair
  {
    const float inv = expf(-(float)pair * (9.2103403719761836f / 64.f));
    float sn, cs; sincosf(tf * inv, &sn, &cs);
    const float q1 = bf2f(qb[base + pair]);
    const float q2 = bf2f(qb[base + 64 + pair]);
    qb[base + pair]      = f2bf(q1 * cs - q2 * sn);
    qb[base + 64 + pair] = f2bf(q1 * sn + q2 * cs);
  }
  // k: storage slot `pair` holds logical dh = pair ^ ((t&7)<<3)
  {
    const int pl = pair ^ ((t & 7) << 3);
    const float inv = expf(-(float)pl * (9.2103403719761836f / 64.f));
    float sn, cs; sincosf(tf * inv, &sn, &cs);
    const float k1 = bf2f(kb[base + pair]);
    const float k2 = bf2f(kb[base + 64 + pair]);
    kb[base + pair]      = f2bf(k1 * cs - k2 * sn);
    kb[base + 64 + pair] = f2bf(k1 * sn + k2 * cs);
  }
}

// ---------------- causal flash attention v6: async-DMA staging -------------
template<bool MASK>
__device__ __forceinline__ void attn_tile(
    int kt0, int qbase, int wave, int row16, int quad,
    const bf16x8 (&qf)[4],
    u16 (&k_s)[64][128], u16 (&vt_s)[128][64], u16 (&p_s)[4][16][72],
    f32x4 (&o_acc)[8], float (&l_acc)[4])
{
  const float scale = 0.08838834764831845f;  // 1/sqrt(128)
  const f32x4 zero = {0.f, 0.f, 0.f, 0.f};
  const int fx = (row16 & 7) << 3;           // XOR de-swizzle
  f32x4 s_acc[4];
  #pragma unroll
  for (int nt = 0; nt < 4; nt++) s_acc[nt] = zero;
  #pragma unroll
  for (int st = 0; st < 4; st++)
    #pragma unroll
    for (int nt = 0; nt < 4; nt++){
      const bf16x8 kf = *(const bf16x8*)&k_s[nt * 16 + row16][(st * 32 + quad * 8) ^ fx];
      s_acc[nt] = __builtin_amdgcn_mfma_f32_16x16x32_bf16(qf[st], kf, s_acc[nt], 0, 0, 0);
    }
  #pragma unroll
  for (int r = 0; r < 4; r++){
    float ps = 0.f;
    #pragma unroll
    for (int nt = 0; nt < 4; nt++){
      float p = __expf(s_acc[nt][r] * scale);
      if (MASK){
        const int qr = qbase + quad * 4 + r;
        if (kt0 + nt * 16 + row16 > qr) p = 0.f;
      }
      ps += p;
      p_s[wave][quad * 4 + r][nt * 16 + row16] = f2bf(p);
    }
    l_acc[r] += ps;
  }
  asm volatile("" ::: "memory");  // p_s wave-private; DS in-order per wave

  #pragma unroll
  for (int kk = 0; kk < 2; kk++){
    const bf16x8 pf = *(const bf16x8*)&p_s[wave][row16][kk * 32 + quad * 8];
    #pragma unroll
    for (int nd = 0; nd < 8; nd++){
      const bf16x8 vb = *(const bf16x8*)&vt_s[nd * 16 + row16][(kk * 32 + quad * 8) ^ fx];
      o_acc[nd] = __builtin_amdgcn_mfma_f32_16x16x32_bf16(pf, vb, o_acc[nd], 0, 0, 0);
    }
  }
}

__global__ __launch_bounds__(256)
void attn_fwd(const u16* __restrict__ q, const u16* __restrict__ k,
              const u16* __restrict__ vtg, u16* __restrict__ ctx){
  __shared__ u16 k_s[64][128];     // dense [key][dh'], DMA-staged
  __shared__ u16 vt_s[128][64];    // dense [dh][t'], DMA-staged
  __shared__ u16 p_s[4][16][72];   // per-wave P [q][key]
  const int tid = threadIdx.x;
  const int wave = tid >> 6, lane = tid & 63;
  const int row16 = lane & 15, quad = lane >> 4;
  const int bh = blockIdx.y;
  const int q0 = (31 - blockIdx.x) * 64;   // heavy blocks dispatch first
  const int qbase = q0 + wave * 16;
  const size_t bho = (size_t)bh * TT * DH;

  bf16x8 qf[4];
  {
    const u16* qp = q + bho + (size_t)(qbase + row16) * DH + quad * 8;
    #pragma unroll
    for (int st = 0; st < 4; st++) qf[st] = *(const bf16x8*)(qp + st * 32);
  }

  float l_acc[4] = {0.f, 0.f, 0.f, 0.f};
  const f32x4 zero = {0.f, 0.f, 0.f, 0.f};
  f32x4 o_acc[8];
  #pragma unroll
  for (int i = 0; i < 8; i++) o_acc[i] = zero;

  // DMA lane maps: K 1KB = 4 rows x 256B; V 1KB = 8 rows x 128B
  const int kl_r = lane >> 4, kl_c = (lane & 15) * 8;
  const int vl_r = lane >> 3, vl_c = (lane & 7) * 8;

  for (int kt0 = 0; kt0 < q0 + 64; kt0 += 64){
    // K: wave stages rows [16w, 16w+16) via 4 async 1KB DMAs
    #pragma unroll
    for (int i = 0; i < 4; i++){
      const int rb = wave * 16 + i * 4;
      gl_lds16(k + bho + (size_t)(kt0 + rb + kl_r) * DH + kl_c, &k_s[rb][0]);
    }
    // V: panel (kt0/64) is 16KB contiguous; wave stages dh [32w, 32w+32)
    const u16* vpan = vtg + ((size_t)bh * 32 + (kt0 >> 6)) * 8192;
    #pragma unroll
    for (int i = 0; i < 4; i++){
      const int rb = wave * 32 + i * 8;
      gl_lds16(vpan + (size_t)(rb + vl_r) * 64 + vl_c, &vt_s[rb][0]);
    }
    __syncthreads();   // compiler drains vmcnt(0) -> DMA complete

    if (kt0 < q0)
      attn_tile<false>(kt0, qbase, wave, row16, quad, qf, k_s, vt_s, p_s, o_acc, l_acc);
    else
      attn_tile<true >(kt0, qbase, wave, row16, quad, qf, k_s, vt_s, p_s, o_acc, l_acc);

    __syncthreads();   // protect restage
  }

  #pragma unroll
  for (int r = 0; r < 4; r++){
    #pragma unroll
    for (int off = 1; off < 16; off <<= 1) l_acc[r] += __shfl_xor(l_acc[r], off, 64);
  }

  const int b = bh >> 4, h = bh & 15;
  #pragma unroll
  for (int nd = 0; nd < 8; nd++){
    #pragma unroll
    for (int r = 0; r < 4; r++){
      const int qr = qbase + quad * 4 + r;
      const size_t off = ((size_t)b * TT + qr) * DM + h * DH + nd * 16 + row16;
      ctx[off] = f2bf(o_acc[nd][r] / l_acc[r]);
    }
  }
}

extern "C" void kernel_launch(void* const* d_in, const int* in_sizes, int n_in,
                              void* d_out, int out_size, void* d_ws, size_t ws_size,
                              hipStream_t stream){
  const float* x  = (const float*)d_in[0];   // fp32 per reference
  const float* wq = (const float*)d_in[1];
  const float* wk = (const float*)d_in[2];
  const float* wv = (const float*)d_in[3];
  const float* wo = (const float*)d_in[4];
  const int* pos  = (const int*)d_in[5];

  char* ws = (char*)d_ws;
  const dim3 tg(64, 64), tb(32, 8);

  if (ws_size >= 92274688ull){
    // fused path: xb 16MB | wt3 25.2MB | qb 16 | kb 16 | vtg 16 = 92.3MB
    u16* xb  = (u16*)ws;                  u16* cb = xb;
    u16* wt3 = (u16*)(ws + 16777216);
    u16* qb  = (u16*)(ws + 41943040);
    u16* kb  = (u16*)(ws + 58720256);
    u16* vtg = (u16*)(ws + 75497472);

    cvt_f32_bf16<<<8192, 256, 0, stream>>>(x, xb, 2097152);
    transpose3<<<dim3(64, 64, 3), tb, 0, stream>>>(wq, wk, wv, wt3);
    gemm_bt2<<<dim3(32, 16, 3), 256, 0, stream>>>(xb, wt3, qb, kb, vtg, 1);
    transpose2048<<<tg, tb, 0, stream>>>(wo, wt3);   // slot0 (wq^T) dead; hoisted
    rope2<<<16384, 256, 0, stream>>>(qb, kb, pos);
    attn_fwd<<<dim3(32, 32), 256, 0, stream>>>(qb, kb, vtg, cb);
    gemm_bt2<<<dim3(32, 16, 1), 256, 0, stream>>>(cb, wt3, d_out, 0, 0, 0);
  } else {
    // fallback (75.5MB): xb/cb 16 | wt 8 | qb 16 | kb 16 | vtg 16
    u16* xb  = (u16*)ws;                  u16* cb = xb;
    u16* wt  = (u16*)(ws + 16777216);
    u16* qb  = (u16*)(ws + 25165824);
    u16* kb  = (u16*)(ws + 41943040);
    u16* vtg = (u16*)(ws + 58720256);

    cvt_f32_bf16<<<8192, 256, 0, stream>>>(x, xb, 2097152);
    transpose2048<<<tg, tb, 0, stream>>>(wq, wt);
    gemm_bt<<<dim3(32, 16, 1), 256, 0, stream>>>(xb, wt, qb, 0, 0, 1);
    transpose2048<<<tg, tb, 0, stream>>>(wk, wt);
    gemm_bt<<<dim3(32, 16, 1), 256, 0, stream>>>(xb, wt, kb, 0, 0, 3);
    transpose2048<<<tg, tb, 0, stream>>>(wv, wt);
    gemm_bt<<<dim3(32, 16, 1), 256, 0, stream>>>(xb, wt, vtg, 0, 0, 2);
    rope2<<<16384, 256, 0, stream>>>(qb, kb, pos);
    attn_fwd<<<dim3(32, 32), 256, 0, stream>>>(qb, kb, vtg, cb);
    transpose2048<<<tg, tb, 0, stream>>>(wo, wt);
    gemm_bt<<<dim3(32, 16, 1), 256, 0, stream>>>(cb, wt, d_out, 0, 0, 0);
  }
}